// Round 6
// baseline (1046.021 us; speedup 1.0000x reference)
//
#include <hip/hip_runtime.h>
#include <stdint.h>

// Problem constants (setup_inputs fixed: S=96, B=2, N=200000, C=67, D=32, K=128)
#define S_   96
#define P_   98              // S+2 padded grid
#define NB_  2
#define GSZ  (NB_*P_*P_*P_)  // 1,882,384 cells
#define C_   67
#define CP_  68              // padded clussum row stride (272 B, 16B-aligned)
#define D_   32
#define KTOP 128
#define SELCAP 1024

typedef unsigned int u32;
typedef unsigned long long u64;

struct Ctrl {
  u64 prefix;
  int n_peaks;
  int kk;
  int selctr;
  int nseg;
};

__device__ __forceinline__ int cell4(int b, int x, int y, int z) {
  return ((b*P_ + x + 1)*P_ + y + 1)*P_ + z + 1;
}

// clear grids + cnts (clussum rows handled selectively in k_fabzero)
__global__ __launch_bounds__(256) void k_clear(int4* __restrict__ rank, int4* __restrict__ cgrid,
                                               int4* __restrict__ vgrid, int4* __restrict__ cnts, int N) {
  const int R4 = GSZ/4;
  const int N4 = N/4;
  int idx = blockIdx.x*256 + threadIdx.x;
  int stride = gridDim.x*256;
  const int4 z = make_int4(0,0,0,0), m1 = make_int4(-1,-1,-1,-1);
  for (int i = idx; i < R4; i += stride) { rank[i] = z; cgrid[i] = m1; vgrid[i] = m1; }
  for (int i = idx; i < N4; i += stride) cnts[i] = z;
}

__global__ __launch_bounds__(1024) void k_init(Ctrl* c, int* __restrict__ hist) {
  int t = threadIdx.x;
  for (int i = t; i < 65536; i += 1024) hist[i] = 0;
  if (t == 0) { c->prefix = 0ull; c->n_peaks = 0; c->kk = KTOP; c->selctr = 0; }
}

// keys + occupancy + voxel grid
__global__ __launch_bounds__(256) void k_key(const int* __restrict__ vc, const float* __restrict__ offs,
                                             int* __restrict__ keyA, int* __restrict__ rank,
                                             int* __restrict__ vgrid, int N) {
  int i = blockIdx.x*256 + threadIdx.x;
  if (i >= N) return;
  const int4 q = ((const int4*)vc)[i];
  int ox = (int)offs[3*i], oy = (int)offs[3*i+1], oz = (int)offs[3*i+2];
  int k = cell4(q.x, q.y+ox, q.z+oy, q.w+oz);
  keyA[i] = k;
  rank[k] = 1;
  vgrid[cell4(q.x, q.y, q.z, q.w)] = i;
}

// ---- exclusive scan over GSZ ints ----
#define SC_TPB 256
#define SC_EPT 8
#define SC_EPB (SC_TPB*SC_EPT)

__global__ __launch_bounds__(SC_TPB) void k_scan1(int* __restrict__ a, int* __restrict__ bsum, int n) {
  __shared__ int sd[SC_TPB];
  int t = threadIdx.x;
  int base = blockIdx.x*SC_EPB + t*SC_EPT;
  int x[SC_EPT]; int s = 0;
  #pragma unroll
  for (int e = 0; e < SC_EPT; ++e) { int idx = base+e; x[e] = (idx < n) ? a[idx] : 0; s += x[e]; }
  sd[t] = s; __syncthreads();
  for (int off = 1; off < SC_TPB; off <<= 1) {
    int v = (t >= off) ? sd[t-off] : 0; __syncthreads(); sd[t] += v; __syncthreads();
  }
  int run = sd[t] - s;
  #pragma unroll
  for (int e = 0; e < SC_EPT; ++e) { int idx = base+e; if (idx < n) a[idx] = run; run += x[e]; }
  if (t == SC_TPB-1) bsum[blockIdx.x] = sd[t];
}

__global__ __launch_bounds__(SC_TPB) void k_scan2(int* __restrict__ bsum, int nb, Ctrl* ctrl) {
  __shared__ int sd[SC_TPB];
  int t = threadIdx.x;
  int x[4]; int s = 0;
  #pragma unroll
  for (int e = 0; e < 4; ++e) { int idx = t*4+e; x[e] = (idx < nb) ? bsum[idx] : 0; s += x[e]; }
  sd[t] = s; __syncthreads();
  for (int off = 1; off < SC_TPB; off <<= 1) {
    int v = (t >= off) ? sd[t-off] : 0; __syncthreads(); sd[t] += v; __syncthreads();
  }
  int run = sd[t] - s;
  #pragma unroll
  for (int e = 0; e < 4; ++e) { int idx = t*4+e; if (idx < nb) bsum[idx] = run; run += x[e]; }
  if (t == SC_TPB-1) ctrl->nseg = sd[t];   // total unique cells
}

__global__ __launch_bounds__(SC_TPB) void k_scan3(int* __restrict__ a, const int* __restrict__ bsum, int n) {
  int add = bsum[blockIdx.x];
  int base = blockIdx.x*SC_EPB + threadIdx.x*SC_EPT;
  #pragma unroll
  for (int e = 0; e < SC_EPT; ++e) { int idx = base+e; if (idx < n) a[idx] += add; }
}

__global__ __launch_bounds__(256) void k_seg(const int* __restrict__ keyA, const int* __restrict__ rank,
                                             int* __restrict__ seg, int* __restrict__ cnts,
                                             int* __restrict__ cgrid, int* __restrict__ ckey, int N) {
  int i = blockIdx.x*256 + threadIdx.x;
  if (i >= N) return;
  int k = keyA[i];
  int s = rank[k];
  seg[i] = s;
  atomicAdd(&cnts[s], 1);
  cgrid[k] = s;
  ckey[s] = k;
}

// fab + g2 + zero multi-count clussum rows (only ~6.5% of rows need zeroing for atomics)
__global__ __launch_bounds__(256) void k_fabzero(const int* __restrict__ seg, const int* __restrict__ cnts,
                                                 const float* __restrict__ cent, float2* __restrict__ fab,
                                                 int* __restrict__ g2, float* __restrict__ clussum, int N) {
  int i = blockIdx.x*256 + threadIdx.x;
  if (i >= N) return;
  int s = seg[i];
  int c = cnts[s];
  fab[i] = make_float2(cent[i], (float)c);
  g2[i] = seg[s];
  if (c > 1) {
    float4* row = (float4*)(clussum + (size_t)s*CP_);
    const float4 fz = make_float4(0.f,0.f,0.f,0.f);
    #pragma unroll
    for (int k = 0; k < CP_/4; ++k) row[k] = fz;   // duplicate writers all write 0 — benign
  }
}

// clussum[s] = mean of feats rows (wave per voxel: coalesced row read, row store / atomics)
__global__ __launch_bounds__(256) void k_accum(const int* __restrict__ seg, const int* __restrict__ cnts,
                                               const float* __restrict__ feats,
                                               float* __restrict__ clussum, int N) {
  int t = threadIdx.x;
  int i = blockIdx.x*4 + (t >> 6);
  if (i >= N) return;
  int lane = t & 63;
  int s = seg[i];          // wave-uniform broadcast load
  int cnt = cnts[s];
  float inv = 1.0f/(float)cnt;
  const float* fr = feats + (size_t)i*C_;
  float* dst = clussum + (size_t)s*CP_;
  float v0 = fr[lane]*inv;
  float v1 = (lane < C_-64) ? fr[64+lane]*inv : 0.f;
  if (cnt == 1) {
    dst[lane] = v0;
    if (lane < C_-64) dst[64+lane] = v1;
  } else {
    atomicAdd(&dst[lane], v0);
    if (lane < C_-64) atomicAdd(&dst[64+lane], v1);
  }
}

// fused: 3x3x3 avg pool over cluster cells + V[s] = relu(pooled @ W_desc)
// 2 segments per wave; all 27 neighbor ids from ONE gather; shfl-broadcast unrolled loop.
__global__ __launch_bounds__(64) void k_pool(const Ctrl* __restrict__ ctrl,
                                             const int* __restrict__ ckey, const int* __restrict__ cgrid,
                                             const float* __restrict__ clussum, const float* __restrict__ Wd,
                                             float* __restrict__ V) {
  int nseg = ctrl->nseg;
  int s0 = blockIdx.x*2;
  if (s0 >= nseg) return;
  int t = threadIdx.x;
  int half = t >> 5, l = t & 31;
  int s = s0 + half;
  bool segok = (s < nseg);           // A-half always ok; B-half may be past end
  int j = -1;
  if (segok && l < 27) {
    int dx = l/9 - 1, dy = (l/3)%3 - 1, dz = l%3 - 1;
    j = cgrid[ckey[s] + (dx*P_ + dy)*P_ + dz];
  }
  float a0 = 0.f, a1 = 0.f, b0 = 0.f, b1 = 0.f;
  int nva = 0, nvb = 0;
  #pragma unroll
  for (int k = 0; k < 27; ++k) {
    int ja = __shfl(j, k);           // wave-uniform (readlane)
    int jb = __shfl(j, 32 + k);
    if (ja >= 0) {
      const float* r = clussum + (size_t)ja*CP_;
      a0 += r[t];
      if (t < 3) a1 += r[64 + t];
      ++nva;
    }
    if (jb >= 0) {
      const float* r = clussum + (size_t)jb*CP_;
      b0 += r[t];
      if (t < 3) b1 += r[64 + t];
      ++nvb;
    }
  }
  __shared__ float pL[2][CP_];
  float inva = 1.f/(float)(nva > 0 ? nva : 1);   // nva>=1 (self) for valid A
  pL[0][t] = a0*inva;
  if (t < 3) pL[0][64 + t] = a1*inva;
  if (s0 + 1 < nseg) {
    float invb = 1.f/(float)(nvb > 0 ? nvb : 1);
    pL[1][t] = b0*invb;
    if (t < 3) pL[1][64 + t] = b1*invb;
  }
  __syncthreads();                   // single wave: compiles to waitcnt
  if (segok) {
    const float* p = pL[half];
    float acc = 0.f;
    #pragma unroll
    for (int c = 0; c < C_; ++c) acc += p[c] * Wd[c*D_ + l];   // halves read same Wd addr (broadcast)
    V[(size_t)s*D_ + l] = fmaxf(acc, 0.f);
  }
}

__global__ __launch_bounds__(256) void k_mixer(const int* __restrict__ vc, const int* __restrict__ vgrid,
                                               const float2* __restrict__ fab, const float* __restrict__ mW,
                                               const float* __restrict__ mB, float* __restrict__ out, int N) {
  int i = blockIdx.x*256 + threadIdx.x;
  if (i >= N) return;
  const int4 q = ((const int4*)vc)[i];
  int bc = cell4(q.x, q.y, q.z, q.w);
  float mix = mB[0];
  #pragma unroll
  for (int k = 0; k < 27; ++k) {
    int dx = k/9 - 1, dy = (k/3)%3 - 1, dz = k%3 - 1;
    int j = vgrid[bc + (dx*P_ + dy)*P_ + dz];
    int jc = (j >= 0) ? j : 0;
    float2 f = fab[jc];
    float msk = (j >= 0) ? 1.f : 0.f;
    mix += msk * (f.x*mW[2*k] + f.y*mW[2*k+1]);
  }
  out[i] = 1.f/(1.f + expf(-mix));
}

__global__ __launch_bounds__(256) void k_peak(const int* __restrict__ vc, const int* __restrict__ vgrid,
                                              const float* __restrict__ out, Ctrl* __restrict__ ctrl,
                                              u64* __restrict__ cand, int N) {
  int i = blockIdx.x*256 + threadIdx.x;
  if (i >= N) return;
  const float NINF = __int_as_float(0xff800000);
  float sc = out[i];
  const int4 q = ((const int4*)vc)[i];
  int bc = cell4(q.x, q.y, q.z, q.w);
  float hmax = NINF;
  #pragma unroll
  for (int k = 0; k < 27; ++k) {
    int dx = k/9 - 1, dy = (k/3)%3 - 1, dz = k%3 - 1;
    int j = vgrid[bc + (dx*P_ + dy)*P_ + dz];
    int jc = (j >= 0) ? j : 0;
    float sj = out[jc];
    float vj = (j >= 0 && sj > 0.1f) ? sj : NINF;
    hmax = fmaxf(hmax, vj);
  }
  if (sc > 0.2f && hmax == sc) {
    int pos = atomicAdd(&ctrl->n_peaks, 1);
    cand[pos] = ((u64)__float_as_uint(sc) << 32) | (u32)(~(u32)i);
  }
}

// 2 radix passes over the 32-bit score (exact score threshold; index ties resolved in k_rank)
__global__ __launch_bounds__(256) void k_hist(const u64* __restrict__ cand, const Ctrl* __restrict__ ctrl,
                                              int* __restrict__ hist, int shift) {
  int idx = blockIdx.x*256 + threadIdx.x;
  if (idx >= ctrl->n_peaks) return;
  u64 key = cand[idx];
  if (shift != 48 && (((key ^ ctrl->prefix) >> (shift + 16)) != 0)) return;
  atomicAdd(&hist[(int)((key >> shift) & 0xFFFF)], 1);
}

__global__ __launch_bounds__(1024) void k_scansel(int* __restrict__ hist, Ctrl* __restrict__ ctrl, int shift) {
  __shared__ int sd[1024];
  int t = threadIdx.x;
  int kk = ctrl->kk;
  int lo = 65536 - (t+1)*64;
  int s = 0;
  for (int b = lo; b < lo+64; ++b) s += hist[b];
  sd[t] = s; __syncthreads();
  for (int off = 1; off < 1024; off <<= 1) {
    int v = (t >= off) ? sd[t-off] : 0; __syncthreads(); sd[t] += v; __syncthreads();
  }
  int before = sd[t] - s;
  if (before < kk && before + s >= kk) {
    int cum = before;
    for (int b = lo+63; b >= lo; --b) {
      int h = hist[b];
      if (cum + h >= kk) { ctrl->prefix |= ((u64)(u32)b) << shift; ctrl->kk = kk - cum; break; }
      cum += h;
    }
  }
  __syncthreads();
  for (int b = lo; b < lo+64; ++b) hist[b] = 0;
}

// collect all keys with score >= exact threshold score (<=127 strictly-above + score-ties)
__global__ __launch_bounds__(256) void k_collect(const u64* __restrict__ cand, Ctrl* __restrict__ ctrl,
                                                 u64* __restrict__ sel) {
  int idx = blockIdx.x*256 + threadIdx.x;
  int np = ctrl->n_peaks;
  if (idx >= np) return;
  u64 key = cand[idx];
  bool take = (np <= KTOP) ? true : ((u32)(key >> 32) >= (u32)(ctrl->prefix >> 32));
  if (take) { int pos = atomicAdd(&ctrl->selctr, 1); if (pos < SELCAP) sel[pos] = key; }
}

// exact rank among collected (full 64-bit keys: score desc, index asc), emit top-128
__global__ __launch_bounds__(SELCAP) void k_rank(const u64* __restrict__ sel, const Ctrl* __restrict__ ctrl,
                                                 float* __restrict__ out, int* __restrict__ topidx, int N) {
  __shared__ u64 sk[SELCAP];
  int t = threadIdx.x;
  int ns = ctrl->selctr; if (ns > SELCAP) ns = SELCAP;
  if (t < KTOP) { out[N + t] = 0.f; topidx[t] = -1; }
  sk[t] = (t < ns) ? sel[t] : 0ull;
  __syncthreads();
  if (t < ns) {
    u64 my = sk[t];
    int r = 0;
    for (int m = 0; m < ns; ++m) r += (sk[m] > my) ? 1 : 0;
    if (r < KTOP) {
      out[N + r] = __uint_as_float((u32)(my >> 32));
      topidx[r]  = (int)~(u32)(my & 0xFFFFFFFFull);
    }
  }
}

// descriptors: row 0 = bg; row 1+r = conf_r * V[seg[idx_r]]
__global__ void k_desc(const int* __restrict__ topidx, const int* __restrict__ seg,
                       const float* __restrict__ V, const float* __restrict__ bg,
                       const float* __restrict__ outc, float* __restrict__ descg, int N) {
  int b = blockIdx.x; int d = threadIdx.x;
  if (b == 0) { descg[d] = bg[d]; return; }
  int r = b - 1;
  int ti = topidx[r];
  float v = 0.f;
  if (ti >= 0) v = outc[N + r] * V[(size_t)seg[ti]*D_ + d];
  descg[b*D_ + d] = v;
}

// instance[i][j] = V[g2[i]] . descriptors[j]
// R5 confirmed: exact writes at 256 threads / VGPR=188, but occupancy 9.4% (2 waves/SIMD
// band) -> latency-bound at 900 GB/s. THIS ROUND: cross the 128-VGPR occupancy threshold
// WITHOUT spilling: (a) register blocking halved to 2 rows x 4 cols per half-wave
// (acc 8 + uv 8 transient, live set ~60-80), (b) __launch_bounds__(256,4) caps at 128
// VGPR -> 4 waves/SIMD, 16 waves/CU (LDS 34.8KB still allows 4 blk/CU).
// Spill tripwire: VGPR==128 exactly AND WRITE_SIZE>120MB => cap caused spills, revert.
// Proven-kept: VPB=128, permuted dsT (lane-contiguous ds_read_b128 = 4 col-groups),
// exact-write column-strided dword stores, unroll-1 chunk loop. FP order unchanged.
#define VPB 128
__global__ __launch_bounds__(256, 4) void k_inst(const int* __restrict__ g2, const float* __restrict__ V,
                                                 const float* __restrict__ descg, float* __restrict__ out, int N) {
  __shared__ __align__(16) float dsT[32*136];   // dsT[d*136 + 4*c + r] = descg[(c+32r)*32 + d]
  __shared__ __align__(16) float ds128[32];     // descg row c=128
  __shared__ __align__(16) float us[VPB*D_];    // us[v*32 + d]
  __shared__ int gs[VPB];
  int tid = threadIdx.x;
  // stage descg transposed+permuted
  for (int idx = tid; idx < 128*D_; idx += 256) {
    int d = idx >> 7, cc = idx & 127;
    dsT[d*136 + ((cc & 31) << 2) + (cc >> 5)] = descg[cc*D_ + d];
  }
  if (tid < 32) ds128[tid] = descg[128*D_ + tid];
  int v0 = blockIdx.x*VPB;
  if (tid < VPB) { int v = v0 + tid; gs[tid] = (v < N) ? g2[v] : -1; }
  __syncthreads();
  for (int idx = tid; idx < VPB*D_; idx += 256) {
    int v = idx >> 5, d = idx & 31; int g = gs[v];
    us[idx] = (g >= 0) ? V[(size_t)g*D_ + d] : 0.f;
  }
  __syncthreads();
  int hw = tid >> 5, tx = tid & 31;   // 8 half-waves of 32 lanes
  #pragma unroll 1
  for (int s = 0; s < 8; ++s) {
    int vb = s*16 + hw*2;             // 2 rows per half-wave per chunk; 8 hw x 2 = 16 rows/chunk
    float4 acc[2];                    // acc[k].{x,y,z,w} = cols {tx,tx+32,tx+64,tx+96} of row vb+k
    #pragma unroll
    for (int k = 0; k < 2; ++k) acc[k] = make_float4(0.f,0.f,0.f,0.f);
    float a128[2] = {0.f, 0.f};
    #pragma unroll
    for (int d4 = 0; d4 < 8; ++d4) {
      float4 uv[2];
      #pragma unroll
      for (int k = 0; k < 2; ++k) uv[k] = *(const float4*)(us + (vb+k)*D_ + d4*4);  // half-wave-uniform: broadcast
      #pragma unroll
      for (int dd = 0; dd < 4; ++dd) {
        float4 dv = *(const float4*)(dsT + (size_t)(d4*4+dd)*136 + tx*4);  // contiguous across lanes
        #pragma unroll
        for (int k = 0; k < 2; ++k) {
          float u = (dd==0) ? uv[k].x : (dd==1) ? uv[k].y : (dd==2) ? uv[k].z : uv[k].w;
          acc[k].x += u*dv.x; acc[k].y += u*dv.y; acc[k].z += u*dv.z; acc[k].w += u*dv.w;
        }
      }
      if (tx == 0) {
        float4 e = *(const float4*)(ds128 + d4*4);
        #pragma unroll
        for (int k = 0; k < 2; ++k)
          a128[k] += uv[k].x*e.x + uv[k].y*e.y + uv[k].z*e.z + uv[k].w*e.w;
      }
    }
    #pragma unroll
    for (int k = 0; k < 2; ++k) {
      int gv = v0 + vb + k;
      if (gv < N) {
        float* o = out + (size_t)gv*129;
        o[tx]      = acc[k].x;         // R1/R5-proven-exact pattern: 4 x 128B-contiguous dword stores
        o[tx + 32] = acc[k].y;
        o[tx + 64] = acc[k].z;
        o[tx + 96] = acc[k].w;
        if (tx == 0) o[128] = a128[k];
      }
    }
  }
}

extern "C" void kernel_launch(void* const* d_in, const int* in_sizes, int n_in,
                              void* d_out, int out_size, void* d_ws, size_t ws_size,
                              hipStream_t stream) {
  const int*   vc    = (const int*)d_in[0];
  const float* feats = (const float*)d_in[1];
  const float* cent  = (const float*)d_in[2];
  const float* offs  = (const float*)d_in[3];
  const float* bg    = (const float*)d_in[4];
  const float* Wd    = (const float*)d_in[5];
  const float* mW    = (const float*)d_in[6];
  const float* mB    = (const float*)d_in[7];
  int N = in_sizes[2];

  float* out = (float*)d_out;   // [0,N) refined | [N,N+128) conf | [N+128,...) instance [N,129]

  uint8_t* base = (uint8_t*)d_ws;
  size_t off = 0;
  auto carve = [&](size_t bytes) -> void* {
    off = (off + 255) & ~(size_t)255;
    void* r = base + off; off += bytes; return r;
  };
  Ctrl*   ctrl    = (Ctrl*)  carve(sizeof(Ctrl));
  int*    keyA    = (int*)   carve((size_t)N*4);
  int*    seg     = (int*)   carve((size_t)N*4);
  int*    cnts    = (int*)   carve((size_t)N*4);
  int*    ckey    = (int*)   carve((size_t)N*4);
  int*    g2      = (int*)   carve((size_t)N*4);
  float2* fab     = (float2*)carve((size_t)N*8);
  int*    rank    = (int*)   carve((size_t)GSZ*4);
  int*    bsum    = (int*)   carve(1024*4);
  int*    cgrid   = (int*)   carve((size_t)GSZ*4);
  int*    vgrid   = (int*)   carve((size_t)GSZ*4);
  float*  clussum = (float*) carve((size_t)N*CP_*4);
  float*  V       = (float*) carve((size_t)N*D_*4);
  u64*    cand    = (u64*)   carve((size_t)N*8);
  int*    hist    = (int*)   carve(65536*4);
  u64*    sel     = (u64*)   carve(SELCAP*8);
  int*    topidx  = (int*)   carve(KTOP*4);
  float*  descg   = (float*) carve(129*D_*4);

  int nb256 = (N + 255)/256;
  int nscan = (GSZ + SC_EPB - 1)/SC_EPB;
  int nclr  = (GSZ/4 + 255)/256;

  k_clear<<<nclr, 256, 0, stream>>>((int4*)rank, (int4*)cgrid, (int4*)vgrid, (int4*)cnts, N);
  k_init<<<1, 1024, 0, stream>>>(ctrl, hist);

  k_key<<<nb256, 256, 0, stream>>>(vc, offs, keyA, rank, vgrid, N);
  k_scan1<<<nscan, SC_TPB, 0, stream>>>(rank, bsum, GSZ);
  k_scan2<<<1, SC_TPB, 0, stream>>>(bsum, nscan, ctrl);
  k_scan3<<<nscan, SC_TPB, 0, stream>>>(rank, bsum, GSZ);
  k_seg<<<nb256, 256, 0, stream>>>(keyA, rank, seg, cnts, cgrid, ckey, N);

  k_fabzero<<<nb256, 256, 0, stream>>>(seg, cnts, cent, fab, g2, clussum, N);
  k_accum<<<(N + 3)/4, 256, 0, stream>>>(seg, cnts, feats, clussum, N);
  k_pool<<<(N + 1)/2, 64, 0, stream>>>(ctrl, ckey, cgrid, clussum, Wd, V);

  k_mixer<<<nb256, 256, 0, stream>>>(vc, vgrid, fab, mW, mB, out, N);
  k_peak<<<nb256, 256, 0, stream>>>(vc, vgrid, out, ctrl, cand, N);

  for (int shift = 48; shift >= 32; shift -= 16) {
    k_hist<<<nb256, 256, 0, stream>>>(cand, ctrl, hist, shift);
    k_scansel<<<1, 1024, 0, stream>>>(hist, ctrl, shift);
  }
  k_collect<<<nb256, 256, 0, stream>>>(cand, ctrl, sel);
  k_rank<<<1, SELCAP, 0, stream>>>(sel, ctrl, out, topidx, N);

  k_desc<<<KTOP + 1, D_, 0, stream>>>(topidx, seg, V, bg, out, descg, N);
  k_inst<<<(N + VPB - 1)/VPB, 256, 0, stream>>>(g2, V, descg, out + N + KTOP, N);
}

// Round 7
// 615.185 us; speedup vs baseline: 1.7003x; 1.7003x over previous
//
#include <hip/hip_runtime.h>
#include <stdint.h>

// Problem constants (setup_inputs fixed: S=96, B=2, N=200000, C=67, D=32, K=128)
#define S_   96
#define P_   98              // S+2 padded grid
#define NB_  2
#define GSZ  (NB_*P_*P_*P_)  // 1,882,384 cells
#define C_   67
#define CP_  68              // padded clussum row stride (272 B, 16B-aligned)
#define D_   32
#define KTOP 128
#define SELCAP 1024

typedef unsigned int u32;
typedef unsigned long long u64;

struct Ctrl {
  u64 prefix;
  int n_peaks;
  int kk;
  int selctr;
  int nseg;
};

__device__ __forceinline__ int cell4(int b, int x, int y, int z) {
  return ((b*P_ + x + 1)*P_ + y + 1)*P_ + z + 1;
}

// clear grids + cnts (clussum rows handled selectively in k_fabzero)
__global__ __launch_bounds__(256) void k_clear(int4* __restrict__ rank, int4* __restrict__ cgrid,
                                               int4* __restrict__ vgrid, int4* __restrict__ cnts, int N) {
  const int R4 = GSZ/4;
  const int N4 = N/4;
  int idx = blockIdx.x*256 + threadIdx.x;
  int stride = gridDim.x*256;
  const int4 z = make_int4(0,0,0,0), m1 = make_int4(-1,-1,-1,-1);
  for (int i = idx; i < R4; i += stride) { rank[i] = z; cgrid[i] = m1; vgrid[i] = m1; }
  for (int i = idx; i < N4; i += stride) cnts[i] = z;
}

__global__ __launch_bounds__(1024) void k_init(Ctrl* c, int* __restrict__ hist) {
  int t = threadIdx.x;
  for (int i = t; i < 65536; i += 1024) hist[i] = 0;
  if (t == 0) { c->prefix = 0ull; c->n_peaks = 0; c->kk = KTOP; c->selctr = 0; }
}

// keys + occupancy + voxel grid
__global__ __launch_bounds__(256) void k_key(const int* __restrict__ vc, const float* __restrict__ offs,
                                             int* __restrict__ keyA, int* __restrict__ rank,
                                             int* __restrict__ vgrid, int N) {
  int i = blockIdx.x*256 + threadIdx.x;
  if (i >= N) return;
  const int4 q = ((const int4*)vc)[i];
  int ox = (int)offs[3*i], oy = (int)offs[3*i+1], oz = (int)offs[3*i+2];
  int k = cell4(q.x, q.y+ox, q.z+oy, q.w+oz);
  keyA[i] = k;
  rank[k] = 1;
  vgrid[cell4(q.x, q.y, q.z, q.w)] = i;
}

// ---- exclusive scan over GSZ ints ----
#define SC_TPB 256
#define SC_EPT 8
#define SC_EPB (SC_TPB*SC_EPT)

__global__ __launch_bounds__(SC_TPB) void k_scan1(int* __restrict__ a, int* __restrict__ bsum, int n) {
  __shared__ int sd[SC_TPB];
  int t = threadIdx.x;
  int base = blockIdx.x*SC_EPB + t*SC_EPT;
  int x[SC_EPT]; int s = 0;
  #pragma unroll
  for (int e = 0; e < SC_EPT; ++e) { int idx = base+e; x[e] = (idx < n) ? a[idx] : 0; s += x[e]; }
  sd[t] = s; __syncthreads();
  for (int off = 1; off < SC_TPB; off <<= 1) {
    int v = (t >= off) ? sd[t-off] : 0; __syncthreads(); sd[t] += v; __syncthreads();
  }
  int run = sd[t] - s;
  #pragma unroll
  for (int e = 0; e < SC_EPT; ++e) { int idx = base+e; if (idx < n) a[idx] = run; run += x[e]; }
  if (t == SC_TPB-1) bsum[blockIdx.x] = sd[t];
}

__global__ __launch_bounds__(SC_TPB) void k_scan2(int* __restrict__ bsum, int nb, Ctrl* ctrl) {
  __shared__ int sd[SC_TPB];
  int t = threadIdx.x;
  int x[4]; int s = 0;
  #pragma unroll
  for (int e = 0; e < 4; ++e) { int idx = t*4+e; x[e] = (idx < nb) ? bsum[idx] : 0; s += x[e]; }
  sd[t] = s; __syncthreads();
  for (int off = 1; off < SC_TPB; off <<= 1) {
    int v = (t >= off) ? sd[t-off] : 0; __syncthreads(); sd[t] += v; __syncthreads();
  }
  int run = sd[t] - s;
  #pragma unroll
  for (int e = 0; e < 4; ++e) { int idx = t*4+e; if (idx < nb) bsum[idx] = run; run += x[e]; }
  if (t == SC_TPB-1) ctrl->nseg = sd[t];   // total unique cells
}

__global__ __launch_bounds__(SC_TPB) void k_scan3(int* __restrict__ a, const int* __restrict__ bsum, int n) {
  int add = bsum[blockIdx.x];
  int base = blockIdx.x*SC_EPB + threadIdx.x*SC_EPT;
  #pragma unroll
  for (int e = 0; e < SC_EPT; ++e) { int idx = base+e; if (idx < n) a[idx] += add; }
}

__global__ __launch_bounds__(256) void k_seg(const int* __restrict__ keyA, const int* __restrict__ rank,
                                             int* __restrict__ seg, int* __restrict__ cnts,
                                             int* __restrict__ cgrid, int* __restrict__ ckey, int N) {
  int i = blockIdx.x*256 + threadIdx.x;
  if (i >= N) return;
  int k = keyA[i];
  int s = rank[k];
  seg[i] = s;
  atomicAdd(&cnts[s], 1);
  cgrid[k] = s;
  ckey[s] = k;
}

// fab + g2 + zero multi-count clussum rows (only ~6.5% of rows need zeroing for atomics)
__global__ __launch_bounds__(256) void k_fabzero(const int* __restrict__ seg, const int* __restrict__ cnts,
                                                 const float* __restrict__ cent, float2* __restrict__ fab,
                                                 int* __restrict__ g2, float* __restrict__ clussum, int N) {
  int i = blockIdx.x*256 + threadIdx.x;
  if (i >= N) return;
  int s = seg[i];
  int c = cnts[s];
  fab[i] = make_float2(cent[i], (float)c);
  g2[i] = seg[s];
  if (c > 1) {
    float4* row = (float4*)(clussum + (size_t)s*CP_);
    const float4 fz = make_float4(0.f,0.f,0.f,0.f);
    #pragma unroll
    for (int k = 0; k < CP_/4; ++k) row[k] = fz;   // duplicate writers all write 0 — benign
  }
}

// clussum[s] = mean of feats rows (wave per voxel: coalesced row read, row store / atomics)
__global__ __launch_bounds__(256) void k_accum(const int* __restrict__ seg, const int* __restrict__ cnts,
                                               const float* __restrict__ feats,
                                               float* __restrict__ clussum, int N) {
  int t = threadIdx.x;
  int i = blockIdx.x*4 + (t >> 6);
  if (i >= N) return;
  int lane = t & 63;
  int s = seg[i];          // wave-uniform broadcast load
  int cnt = cnts[s];
  float inv = 1.0f/(float)cnt;
  const float* fr = feats + (size_t)i*C_;
  float* dst = clussum + (size_t)s*CP_;
  float v0 = fr[lane]*inv;
  float v1 = (lane < C_-64) ? fr[64+lane]*inv : 0.f;
  if (cnt == 1) {
    dst[lane] = v0;
    if (lane < C_-64) dst[64+lane] = v1;
  } else {
    atomicAdd(&dst[lane], v0);
    if (lane < C_-64) atomicAdd(&dst[64+lane], v1);
  }
}

// fused: 3x3x3 avg pool over cluster cells + V[s] = relu(pooled @ W_desc)
// 2 segments per wave; all 27 neighbor ids from ONE gather; shfl-broadcast unrolled loop.
__global__ __launch_bounds__(64) void k_pool(const Ctrl* __restrict__ ctrl,
                                             const int* __restrict__ ckey, const int* __restrict__ cgrid,
                                             const float* __restrict__ clussum, const float* __restrict__ Wd,
                                             float* __restrict__ V) {
  int nseg = ctrl->nseg;
  int s0 = blockIdx.x*2;
  if (s0 >= nseg) return;
  int t = threadIdx.x;
  int half = t >> 5, l = t & 31;
  int s = s0 + half;
  bool segok = (s < nseg);           // A-half always ok; B-half may be past end
  int j = -1;
  if (segok && l < 27) {
    int dx = l/9 - 1, dy = (l/3)%3 - 1, dz = l%3 - 1;
    j = cgrid[ckey[s] + (dx*P_ + dy)*P_ + dz];
  }
  float a0 = 0.f, a1 = 0.f, b0 = 0.f, b1 = 0.f;
  int nva = 0, nvb = 0;
  #pragma unroll
  for (int k = 0; k < 27; ++k) {
    int ja = __shfl(j, k);           // wave-uniform (readlane)
    int jb = __shfl(j, 32 + k);
    if (ja >= 0) {
      const float* r = clussum + (size_t)ja*CP_;
      a0 += r[t];
      if (t < 3) a1 += r[64 + t];
      ++nva;
    }
    if (jb >= 0) {
      const float* r = clussum + (size_t)jb*CP_;
      b0 += r[t];
      if (t < 3) b1 += r[64 + t];
      ++nvb;
    }
  }
  __shared__ float pL[2][CP_];
  float inva = 1.f/(float)(nva > 0 ? nva : 1);   // nva>=1 (self) for valid A
  pL[0][t] = a0*inva;
  if (t < 3) pL[0][64 + t] = a1*inva;
  if (s0 + 1 < nseg) {
    float invb = 1.f/(float)(nvb > 0 ? nvb : 1);
    pL[1][t] = b0*invb;
    if (t < 3) pL[1][64 + t] = b1*invb;
  }
  __syncthreads();                   // single wave: compiles to waitcnt
  if (segok) {
    const float* p = pL[half];
    float acc = 0.f;
    #pragma unroll
    for (int c = 0; c < C_; ++c) acc += p[c] * Wd[c*D_ + l];   // halves read same Wd addr (broadcast)
    V[(size_t)s*D_ + l] = fmaxf(acc, 0.f);
  }
}

__global__ __launch_bounds__(256) void k_mixer(const int* __restrict__ vc, const int* __restrict__ vgrid,
                                               const float2* __restrict__ fab, const float* __restrict__ mW,
                                               const float* __restrict__ mB, float* __restrict__ out, int N) {
  int i = blockIdx.x*256 + threadIdx.x;
  if (i >= N) return;
  const int4 q = ((const int4*)vc)[i];
  int bc = cell4(q.x, q.y, q.z, q.w);
  float mix = mB[0];
  #pragma unroll
  for (int k = 0; k < 27; ++k) {
    int dx = k/9 - 1, dy = (k/3)%3 - 1, dz = k%3 - 1;
    int j = vgrid[bc + (dx*P_ + dy)*P_ + dz];
    int jc = (j >= 0) ? j : 0;
    float2 f = fab[jc];
    float msk = (j >= 0) ? 1.f : 0.f;
    mix += msk * (f.x*mW[2*k] + f.y*mW[2*k+1]);
  }
  out[i] = 1.f/(1.f + expf(-mix));
}

__global__ __launch_bounds__(256) void k_peak(const int* __restrict__ vc, const int* __restrict__ vgrid,
                                              const float* __restrict__ out, Ctrl* __restrict__ ctrl,
                                              u64* __restrict__ cand, int N) {
  int i = blockIdx.x*256 + threadIdx.x;
  if (i >= N) return;
  const float NINF = __int_as_float(0xff800000);
  float sc = out[i];
  const int4 q = ((const int4*)vc)[i];
  int bc = cell4(q.x, q.y, q.z, q.w);
  float hmax = NINF;
  #pragma unroll
  for (int k = 0; k < 27; ++k) {
    int dx = k/9 - 1, dy = (k/3)%3 - 1, dz = k%3 - 1;
    int j = vgrid[bc + (dx*P_ + dy)*P_ + dz];
    int jc = (j >= 0) ? j : 0;
    float sj = out[jc];
    float vj = (j >= 0 && sj > 0.1f) ? sj : NINF;
    hmax = fmaxf(hmax, vj);
  }
  if (sc > 0.2f && hmax == sc) {
    int pos = atomicAdd(&ctrl->n_peaks, 1);
    cand[pos] = ((u64)__float_as_uint(sc) << 32) | (u32)(~(u32)i);
  }
}

// 2 radix passes over the 32-bit score (exact score threshold; index ties resolved in k_rank)
__global__ __launch_bounds__(256) void k_hist(const u64* __restrict__ cand, const Ctrl* __restrict__ ctrl,
                                              int* __restrict__ hist, int shift) {
  int idx = blockIdx.x*256 + threadIdx.x;
  if (idx >= ctrl->n_peaks) return;
  u64 key = cand[idx];
  if (shift != 48 && (((key ^ ctrl->prefix) >> (shift + 16)) != 0)) return;
  atomicAdd(&hist[(int)((key >> shift) & 0xFFFF)], 1);
}

__global__ __launch_bounds__(1024) void k_scansel(int* __restrict__ hist, Ctrl* __restrict__ ctrl, int shift) {
  __shared__ int sd[1024];
  int t = threadIdx.x;
  int kk = ctrl->kk;
  int lo = 65536 - (t+1)*64;
  int s = 0;
  for (int b = lo; b < lo+64; ++b) s += hist[b];
  sd[t] = s; __syncthreads();
  for (int off = 1; off < 1024; off <<= 1) {
    int v = (t >= off) ? sd[t-off] : 0; __syncthreads(); sd[t] += v; __syncthreads();
  }
  int before = sd[t] - s;
  if (before < kk && before + s >= kk) {
    int cum = before;
    for (int b = lo+63; b >= lo; --b) {
      int h = hist[b];
      if (cum + h >= kk) { ctrl->prefix |= ((u64)(u32)b) << shift; ctrl->kk = kk - cum; break; }
      cum += h;
    }
  }
  __syncthreads();
  for (int b = lo; b < lo+64; ++b) hist[b] = 0;
}

// collect all keys with score >= exact threshold score (<=127 strictly-above + score-ties)
__global__ __launch_bounds__(256) void k_collect(const u64* __restrict__ cand, Ctrl* __restrict__ ctrl,
                                                 u64* __restrict__ sel) {
  int idx = blockIdx.x*256 + threadIdx.x;
  int np = ctrl->n_peaks;
  if (idx >= np) return;
  u64 key = cand[idx];
  bool take = (np <= KTOP) ? true : ((u32)(key >> 32) >= (u32)(ctrl->prefix >> 32));
  if (take) { int pos = atomicAdd(&ctrl->selctr, 1); if (pos < SELCAP) sel[pos] = key; }
}

// exact rank among collected (full 64-bit keys: score desc, index asc), emit top-128
__global__ __launch_bounds__(SELCAP) void k_rank(const u64* __restrict__ sel, const Ctrl* __restrict__ ctrl,
                                                 float* __restrict__ out, int* __restrict__ topidx, int N) {
  __shared__ u64 sk[SELCAP];
  int t = threadIdx.x;
  int ns = ctrl->selctr; if (ns > SELCAP) ns = SELCAP;
  if (t < KTOP) { out[N + t] = 0.f; topidx[t] = -1; }
  sk[t] = (t < ns) ? sel[t] : 0ull;
  __syncthreads();
  if (t < ns) {
    u64 my = sk[t];
    int r = 0;
    for (int m = 0; m < ns; ++m) r += (sk[m] > my) ? 1 : 0;
    if (r < KTOP) {
      out[N + r] = __uint_as_float((u32)(my >> 32));
      topidx[r]  = (int)~(u32)(my & 0xFFFFFFFFull);
    }
  }
}

// descriptors: row 0 = bg; row 1+r = conf_r * V[seg[idx_r]]
__global__ void k_desc(const int* __restrict__ topidx, const int* __restrict__ seg,
                       const float* __restrict__ V, const float* __restrict__ bg,
                       const float* __restrict__ outc, float* __restrict__ descg, int N) {
  int b = blockIdx.x; int d = threadIdx.x;
  if (b == 0) { descg[d] = bg[d]; return; }
  int r = b - 1;
  int ti = topidx[r];
  float v = 0.f;
  if (ti >= 0) v = outc[N + r] * V[(size_t)seg[ti]*D_ + d];
  descg[b*D_ + d] = v;
}

// instance[i][j] = V[g2[i]] . descriptors[j]
// R5 state (129.6us, exact traffic, VGPR=188 -> 2 waves/SIMD) was latency-bound.
// R6 lesson: explicit __launch_bounds__ min-waves caps cause catastrophic spills on this
// kernel (VGPR forced to 64, FETCH 1.24GB) — caps are OFF the table.
// THIS ROUND: reduce NATURAL pressure instead. R5's 188 VGPR came from the fully-unrolled
// d4 loop software-pipelining all 8 iterations' LDS loads (uv[4]+dv[4] = 32/iter).
// `#pragma unroll 2` bounds the in-flight window -> predicted natural ~96-124 VGPR,
// under the 128 occupancy step (waves/SIMD halve at 64/128/256), with the allocator
// free to avoid spills. Everything else identical to R5 (same FP order, exact stores).
// Tripwire: WRITE>120MB or FETCH>30MB => spills, revert to R5 verbatim.
#define VPB 128
__global__ __launch_bounds__(256) void k_inst(const int* __restrict__ g2, const float* __restrict__ V,
                                              const float* __restrict__ descg, float* __restrict__ out, int N) {
  __shared__ __align__(16) float dsT[32*136];   // dsT[d*136 + 4*c + r] = descg[(c+32r)*32 + d]
  __shared__ __align__(16) float ds128[32];     // descg row c=128
  __shared__ __align__(16) float us[VPB*D_];    // us[v*32 + d]
  __shared__ int gs[VPB];
  int tid = threadIdx.x;
  // stage descg transposed+permuted
  for (int idx = tid; idx < 128*D_; idx += 256) {
    int d = idx >> 7, cc = idx & 127;
    dsT[d*136 + ((cc & 31) << 2) + (cc >> 5)] = descg[cc*D_ + d];
  }
  if (tid < 32) ds128[tid] = descg[128*D_ + tid];
  int v0 = blockIdx.x*VPB;
  if (tid < VPB) { int v = v0 + tid; gs[tid] = (v < N) ? g2[v] : -1; }
  __syncthreads();
  for (int idx = tid; idx < VPB*D_; idx += 256) {
    int v = idx >> 5, d = idx & 31; int g = gs[v];
    us[idx] = (g >= 0) ? V[(size_t)g*D_ + d] : 0.f;
  }
  __syncthreads();
  int hw = tid >> 5, tx = tid & 31;   // 8 half-waves of 32 lanes
  #pragma unroll 1
  for (int s = 0; s < 4; ++s) {
    int vb = s*32 + hw*4;             // 4 rows per half-wave per chunk; 8 hw x 4 = 32 rows/chunk
    float4 acc[4];                    // acc[k].{x,y,z,w} = cols {tx,tx+32,tx+64,tx+96} of row vb+k
    #pragma unroll
    for (int k = 0; k < 4; ++k) acc[k] = make_float4(0.f,0.f,0.f,0.f);
    float a128[4] = {0.f, 0.f, 0.f, 0.f};
    #pragma unroll 2
    for (int d4 = 0; d4 < 8; ++d4) {
      float4 uv[4];
      #pragma unroll
      for (int k = 0; k < 4; ++k) uv[k] = *(const float4*)(us + (vb+k)*D_ + d4*4);  // half-wave-uniform: broadcast
      #pragma unroll
      for (int dd = 0; dd < 4; ++dd) {
        float4 dv = *(const float4*)(dsT + (size_t)(d4*4+dd)*136 + tx*4);  // contiguous across lanes
        #pragma unroll
        for (int k = 0; k < 4; ++k) {
          float u = (dd==0) ? uv[k].x : (dd==1) ? uv[k].y : (dd==2) ? uv[k].z : uv[k].w;
          acc[k].x += u*dv.x; acc[k].y += u*dv.y; acc[k].z += u*dv.z; acc[k].w += u*dv.w;
        }
      }
      if (tx == 0) {
        float4 e = *(const float4*)(ds128 + d4*4);
        #pragma unroll
        for (int k = 0; k < 4; ++k)
          a128[k] += uv[k].x*e.x + uv[k].y*e.y + uv[k].z*e.z + uv[k].w*e.w;
      }
    }
    #pragma unroll
    for (int k = 0; k < 4; ++k) {
      int gv = v0 + vb + k;
      if (gv < N) {
        float* o = out + (size_t)gv*129;
        o[tx]      = acc[k].x;         // R1/R5-proven-exact pattern: 4 x 128B-contiguous dword stores
        o[tx + 32] = acc[k].y;
        o[tx + 64] = acc[k].z;
        o[tx + 96] = acc[k].w;
        if (tx == 0) o[128] = a128[k];
      }
    }
  }
}

extern "C" void kernel_launch(void* const* d_in, const int* in_sizes, int n_in,
                              void* d_out, int out_size, void* d_ws, size_t ws_size,
                              hipStream_t stream) {
  const int*   vc    = (const int*)d_in[0];
  const float* feats = (const float*)d_in[1];
  const float* cent  = (const float*)d_in[2];
  const float* offs  = (const float*)d_in[3];
  const float* bg    = (const float*)d_in[4];
  const float* Wd    = (const float*)d_in[5];
  const float* mW    = (const float*)d_in[6];
  const float* mB    = (const float*)d_in[7];
  int N = in_sizes[2];

  float* out = (float*)d_out;   // [0,N) refined | [N,N+128) conf | [N+128,...) instance [N,129]

  uint8_t* base = (uint8_t*)d_ws;
  size_t off = 0;
  auto carve = [&](size_t bytes) -> void* {
    off = (off + 255) & ~(size_t)255;
    void* r = base + off; off += bytes; return r;
  };
  Ctrl*   ctrl    = (Ctrl*)  carve(sizeof(Ctrl));
  int*    keyA    = (int*)   carve((size_t)N*4);
  int*    seg     = (int*)   carve((size_t)N*4);
  int*    cnts    = (int*)   carve((size_t)N*4);
  int*    ckey    = (int*)   carve((size_t)N*4);
  int*    g2      = (int*)   carve((size_t)N*4);
  float2* fab     = (float2*)carve((size_t)N*8);
  int*    rank    = (int*)   carve((size_t)GSZ*4);
  int*    bsum    = (int*)   carve(1024*4);
  int*    cgrid   = (int*)   carve((size_t)GSZ*4);
  int*    vgrid   = (int*)   carve((size_t)GSZ*4);
  float*  clussum = (float*) carve((size_t)N*CP_*4);
  float*  V       = (float*) carve((size_t)N*D_*4);
  u64*    cand    = (u64*)   carve((size_t)N*8);
  int*    hist    = (int*)   carve(65536*4);
  u64*    sel     = (u64*)   carve(SELCAP*8);
  int*    topidx  = (int*)   carve(KTOP*4);
  float*  descg   = (float*) carve(129*D_*4);

  int nb256 = (N + 255)/256;
  int nscan = (GSZ + SC_EPB - 1)/SC_EPB;
  int nclr  = (GSZ/4 + 255)/256;

  k_clear<<<nclr, 256, 0, stream>>>((int4*)rank, (int4*)cgrid, (int4*)vgrid, (int4*)cnts, N);
  k_init<<<1, 1024, 0, stream>>>(ctrl, hist);

  k_key<<<nb256, 256, 0, stream>>>(vc, offs, keyA, rank, vgrid, N);
  k_scan1<<<nscan, SC_TPB, 0, stream>>>(rank, bsum, GSZ);
  k_scan2<<<1, SC_TPB, 0, stream>>>(bsum, nscan, ctrl);
  k_scan3<<<nscan, SC_TPB, 0, stream>>>(rank, bsum, GSZ);
  k_seg<<<nb256, 256, 0, stream>>>(keyA, rank, seg, cnts, cgrid, ckey, N);

  k_fabzero<<<nb256, 256, 0, stream>>>(seg, cnts, cent, fab, g2, clussum, N);
  k_accum<<<(N + 3)/4, 256, 0, stream>>>(seg, cnts, feats, clussum, N);
  k_pool<<<(N + 1)/2, 64, 0, stream>>>(ctrl, ckey, cgrid, clussum, Wd, V);

  k_mixer<<<nb256, 256, 0, stream>>>(vc, vgrid, fab, mW, mB, out, N);
  k_peak<<<nb256, 256, 0, stream>>>(vc, vgrid, out, ctrl, cand, N);

  for (int shift = 48; shift >= 32; shift -= 16) {
    k_hist<<<nb256, 256, 0, stream>>>(cand, ctrl, hist, shift);
    k_scansel<<<1, 1024, 0, stream>>>(hist, ctrl, shift);
  }
  k_collect<<<nb256, 256, 0, stream>>>(cand, ctrl, sel);
  k_rank<<<1, SELCAP, 0, stream>>>(sel, ctrl, out, topidx, N);

  k_desc<<<KTOP + 1, D_, 0, stream>>>(topidx, seg, V, bg, out, descg, N);
  k_inst<<<(N + VPB - 1)/VPB, 256, 0, stream>>>(g2, V, descg, out + N + KTOP, N);
}